// Round 4
// baseline (786.902 us; speedup 1.0000x reference)
//
#include <hip/hip_runtime.h>
#include <math.h>

#define BB 256
#define SS 256
#define KK 64
#define DD 128

typedef short bf16x8 __attribute__((ext_vector_type(8)));
typedef float f32x4 __attribute__((ext_vector_type(4)));

__device__ __forceinline__ unsigned short bf16_rne(float x) {
  unsigned u = __float_as_uint(x);
  unsigned r = ((u >> 16) & 1u) + 0x7fffu;
  return (unsigned short)((u + r) >> 16);
}

// ---------------------------------------------------------------------------
// Precompute 1: kV[b,k,e] = sum_d keys[b,k,d] * V[d,e]   (fp32)
// ---------------------------------------------------------------------------
__global__ __launch_bounds__(256) void kv_kernel(const float* __restrict__ keys,
                                                 const float* __restrict__ V,
                                                 float* __restrict__ kV)
{
    __shared__ __align__(16) float Ks[KK][DD];
    __shared__ __align__(16) float Vs[DD][DD];
    const int b = blockIdx.x;
    const int t = threadIdx.x;
    const float* kb = keys + (size_t)b * KK * DD;
    for (int i = t; i < KK * DD / 4; i += 256) ((float4*)Ks)[i] = ((const float4*)kb)[i];
    for (int i = t; i < DD * DD / 4; i += 256) ((float4*)Vs)[i] = ((const float4*)V)[i];
    __syncthreads();

    const int e0 = (t & 15) * 8;
    const int k0 = (t >> 4) * 4;
    float acc[4][8];
#pragma unroll
    for (int i = 0; i < 4; ++i)
#pragma unroll
        for (int j = 0; j < 8; ++j) acc[i][j] = 0.f;

#pragma unroll 4
    for (int d = 0; d < DD; ++d) {
        float aa[4] = {Ks[k0 + 0][d], Ks[k0 + 1][d], Ks[k0 + 2][d], Ks[k0 + 3][d]};
        float4 v0 = *(const float4*)&Vs[d][e0];
        float4 v1 = *(const float4*)&Vs[d][e0 + 4];
        float vv[8] = {v0.x, v0.y, v0.z, v0.w, v1.x, v1.y, v1.z, v1.w};
#pragma unroll
        for (int i = 0; i < 4; ++i)
#pragma unroll
            for (int j = 0; j < 8; ++j) acc[i][j] = fmaf(aa[i], vv[j], acc[i][j]);
    }
    float* o = kV + (size_t)b * KK * DD;
#pragma unroll
    for (int i = 0; i < 4; ++i)
#pragma unroll
        for (int j = 0; j < 8; j += 4) {
            float4 w4 = {acc[i][j], acc[i][j + 1], acc[i][j + 2], acc[i][j + 3]};
            *(float4*)&o[(k0 + i) * DD + e0 + j] = w4;
        }
}

// ---------------------------------------------------------------------------
// Precompute 2 (fused): sW[b,t,e] = enc[b,t,:]@W ; sk[b,t,k] = enc[b,t,:].keys[b,k,:]
// ---------------------------------------------------------------------------
__global__ __launch_bounds__(256) void swsk_kernel(const float* __restrict__ enc,
                                                   const float* __restrict__ W,
                                                   const float* __restrict__ keys,
                                                   float* __restrict__ sW,
                                                   float* __restrict__ sk)
{
    __shared__ __align__(16) float Es[64][DD];   // 32 KB
    __shared__ __align__(16) float Ws[DD][DD];   // 64 KB (phase 2: reused for Ks)
    const int blk = blockIdx.x;
    const int b = blk >> 2;
    const int tt = blk & 3;
    const int t = threadIdx.x;
    const float* eb = enc + ((size_t)b * SS + tt * 64) * DD;
    for (int i = t; i < 64 * DD / 4; i += 256) ((float4*)Es)[i] = ((const float4*)eb)[i];
    for (int i = t; i < DD * DD / 4; i += 256) ((float4*)Ws)[i] = ((const float4*)W)[i];
    __syncthreads();

    // ---- phase 1: sW ----
    {
        const int e0 = (t & 15) * 8;
        const int r0 = (t >> 4) * 4;
        float acc[4][8];
#pragma unroll
        for (int i = 0; i < 4; ++i)
#pragma unroll
            for (int j = 0; j < 8; ++j) acc[i][j] = 0.f;
#pragma unroll 4
        for (int d = 0; d < DD; ++d) {
            float aa[4] = {Es[r0 + 0][d], Es[r0 + 1][d], Es[r0 + 2][d], Es[r0 + 3][d]};
            float4 v0 = *(const float4*)&Ws[d][e0];
            float4 v1 = *(const float4*)&Ws[d][e0 + 4];
            float vv[8] = {v0.x, v0.y, v0.z, v0.w, v1.x, v1.y, v1.z, v1.w};
#pragma unroll
            for (int i = 0; i < 4; ++i)
#pragma unroll
                for (int j = 0; j < 8; ++j) acc[i][j] = fmaf(aa[i], vv[j], acc[i][j]);
        }
        float* o = sW + ((size_t)b * SS + tt * 64) * DD;
#pragma unroll
        for (int i = 0; i < 4; ++i)
#pragma unroll
            for (int j = 0; j < 8; j += 4) {
                float4 w4 = {acc[i][j], acc[i][j + 1], acc[i][j + 2], acc[i][j + 3]};
                *(float4*)&o[(r0 + i) * DD + e0 + j] = w4;
            }
    }
    __syncthreads();
    // ---- phase 2: stage keys over Ws, compute sk ----
    {
        float (*Ks)[DD] = (float(*)[DD])Ws;
        const float* kb = keys + (size_t)b * KK * DD;
        for (int i = t; i < KK * DD / 4; i += 256) ((float4*)Ks)[i] = ((const float4*)kb)[i];
        __syncthreads();

        const int r0 = (t >> 4) * 4;
        const int k0 = (t & 15) * 4;
        float acc[4][4];
#pragma unroll
        for (int i = 0; i < 4; ++i)
#pragma unroll
            for (int j = 0; j < 4; ++j) acc[i][j] = 0.f;
#pragma unroll 4
        for (int d = 0; d < DD; ++d) {
            float er[4], kr[4];
#pragma unroll
            for (int i = 0; i < 4; ++i) er[i] = Es[r0 + i][d];
#pragma unroll
            for (int j = 0; j < 4; ++j) kr[j] = Ks[k0 + j][d];
#pragma unroll
            for (int i = 0; i < 4; ++i)
#pragma unroll
                for (int j = 0; j < 4; ++j) acc[i][j] = fmaf(er[i], kr[j], acc[i][j]);
        }
        float* o = sk + ((size_t)b * SS + tt * 64) * KK;
#pragma unroll
        for (int i = 0; i < 4; ++i) {
            float4 w4 = {acc[i][0], acc[i][1], acc[i][2], acc[i][3]};
            *(float4*)&o[(r0 + i) * KK + k0] = w4;
        }
    }
}

// ---------------------------------------------------------------------------
// Precompute 3: U in MFMA B-fragment order, split bf16 hi/lo.
// Ufh/Ufl layout: [ntg(8)][kt(4)][lane(64)][j(8)], value =
//   U[32*kt + 8*(lane>>4) + j][16*ntg + (lane&15)]
// ---------------------------------------------------------------------------
__global__ void ufrag_kernel(const float* __restrict__ U,
                             unsigned short* __restrict__ Ufh,
                             unsigned short* __restrict__ Ufl)
{
    const int blk = blockIdx.x;       // 32 = ntg*4 + kt
    const int l = threadIdx.x;        // 64
    const int ntg = blk >> 2, kt = blk & 3;
    const int e = ntg * 16 + (l & 15);
    const int d0 = kt * 32 + (l >> 4) * 8;
#pragma unroll
    for (int j = 0; j < 8; ++j) {
        float x = U[(d0 + j) * DD + e];
        unsigned short hi = bf16_rne(x);
        float rem = x - __uint_as_float(((unsigned)hi) << 16);
        unsigned short lo = bf16_rne(rem);
        int idx = (blk * 64 + l) * 8 + j;
        Ufh[idx] = hi;
        Ufl[idx] = lo;
    }
}

// ---------------------------------------------------------------------------
// Main kernel. Grid = 1024 (batch x 4 row-groups of 16 rows). Block = 512
// threads = 8 waves; wave w owns cols [16w, 16w+16) -> U frags are only
// 8 x bf16x8 = 32 VGPR/thread (total demand ~85, fits the 128-VGPR cap of
// launch_bounds(512,4) -> no spill, no remat).
// Per step: MFMA (12 acc in 3 indep chains; waves 0-3 add 3 gate MFMA)
// -> B2 -> gate sigmoid (redundant), epilogue, sumsq partial -> B3 ->
// rsqrt, normalize, split-bf16 write to hA, stage next row -> B1.
// ---------------------------------------------------------------------------
__global__ __launch_bounds__(512, 4) void entnet_main(
    const float* __restrict__ enc,   // [B,S,D]
    const int*   __restrict__ mask,  // [B,S]
    const float* __restrict__ sWg,   // [B,S,D]
    const float* __restrict__ skg,   // [B,S,K]
    const float* __restrict__ kVg,   // [B,K,D]
    const unsigned short* __restrict__ Ufh,
    const unsigned short* __restrict__ Ufl,
    float*       __restrict__ out)   // [B,K,D]
{
    __shared__ __align__(16) unsigned short hAhi[4][64][8];   // 4 KB
    __shared__ __align__(16) unsigned short hAlo[4][64][8];   // 4 KB
    __shared__ __align__(16) unsigned short shi_sh[2][DD];
    __shared__ __align__(16) unsigned short slo_sh[2][DD];
    __shared__ __align__(16) float sW_sh[2][DD];
    __shared__ __align__(16) float sk_sh[2][16];
    __shared__ __align__(16) float gpart_sh[4][16];
    __shared__ __align__(16) float rowsq_sh[8][16];
    __shared__ int act_sh[SS];
    __shared__ int m_sh[SS];
    __shared__ int nact_sh;

    // XCD-grouped swizzle: 4 sibling blocks (same b) land on the same XCD.
    const int raw = blockIdx.x;
    const int xcd = raw & 7, slot = raw >> 3;
    const int b = xcd * 32 + (slot >> 2);
    const int rg = slot & 3;                 // rows k in [16rg, 16rg+16)

    const int t = threadIdx.x;
    const int w = t >> 6, l = t & 63;
    const int gi = l >> 4, li = l & 15;
    const int slot_r = l ^ ((l >> 2) & 3);

    // ---- stage mask, zero hA ----
    if (t < SS) m_sh[t] = mask[b * SS + t];
    {
        unsigned int* p = (unsigned int*)&hAhi[0][0][0];
        unsigned int* q = (unsigned int*)&hAlo[0][0][0];
        for (int i = t; i < 4 * 64 * 8 / 2; i += 512) { p[i] = 0u; q[i] = 0u; }
    }
    __syncthreads();
    if (t == 0) {
        int c = 0;
        for (int i = 0; i < SS; ++i) if (m_sh[i]) act_sh[c++] = i;
        nact_sh = c;
    }

    // ---- U fragments (regs): ntg = w, all kt -> 32 VGPR ----
    bf16x8 ufh[4], ufl[4];
#pragma unroll
    for (int kt = 0; kt < 4; ++kt) {
        int off = ((w * 4 + kt) * 64 + l) * 8;
        ufh[kt] = *(const bf16x8*)&Ufh[off];
        ufl[kt] = *(const bf16x8*)&Ufl[off];
    }
    // ---- kV (regs): k = 16rg+4gi+reg, e = 16w+li ----
    float kvreg[4];
#pragma unroll
    for (int reg = 0; reg < 4; ++reg)
        kvreg[reg] = kVg[((size_t)b * KK + 16 * rg + 4 * gi + reg) * DD + 16 * w + li];

    f32x4 hreg = (f32x4){0.f, 0.f, 0.f, 0.f};
    __syncthreads();

    const int nact = nact_sh;
    // ---- prologue: stage rows for act[0] into buffer 0 ----
    if (nact > 0) {
        int t0i = act_sh[0];
        if (t < 128) {
            float x = enc[((size_t)b * SS + t0i) * DD + t];
            unsigned u = __float_as_uint(x);
            shi_sh[0][t] = (unsigned short)(u >> 16);
            float rem = x - __uint_as_float(u & 0xffff0000u);
            slo_sh[0][t] = (unsigned short)(__float_as_uint(rem) >> 16);
        } else if (t < 256) {
            sW_sh[0][t - 128] = sWg[((size_t)b * SS + t0i) * DD + (t - 128)];
        } else if (t < 272) {
            sk_sh[0][t - 256] = skg[((size_t)b * SS + t0i) * KK + 16 * rg + (t - 256)];
        }
    }
    __syncthreads();

    for (int ai = 0; ai < nact; ++ai) {
        const int cur = ai & 1, nxt = cur ^ 1;
        // prefetch next active row (consumed after B3)
        float pf = 0.f;
        const bool have = (ai + 1 < nact);
        if (have) {
            int tn = act_sh[ai + 1];
            if (t < 128)      pf = enc[((size_t)b * SS + tn) * DD + t];
            else if (t < 256) pf = sWg[((size_t)b * SS + tn) * DD + (t - 128)];
            else if (t < 272) pf = skg[((size_t)b * SS + tn) * KK + 16 * rg + (t - 256)];
        }

        // ---- MFMA phase: 3 independent chains + gate partial (waves 0-3) ----
        f32x4 accA = (f32x4){0.f, 0.f, 0.f, 0.f};
        f32x4 accB = (f32x4){0.f, 0.f, 0.f, 0.f};
        f32x4 accC = (f32x4){0.f, 0.f, 0.f, 0.f};
        f32x4 gacc = (f32x4){0.f, 0.f, 0.f, 0.f};
#pragma unroll
        for (int kt = 0; kt < 4; ++kt) {
            bf16x8 ah = *(const bf16x8*)&hAhi[kt][slot_r][0];
            bf16x8 al = *(const bf16x8*)&hAlo[kt][slot_r][0];
            accA = __builtin_amdgcn_mfma_f32_16x16x32_bf16(ah, ufh[kt], accA, 0, 0, 0);
            accB = __builtin_amdgcn_mfma_f32_16x16x32_bf16(al, ufh[kt], accB, 0, 0, 0);
            accC = __builtin_amdgcn_mfma_f32_16x16x32_bf16(ah, ufl[kt], accC, 0, 0, 0);
            if (w == kt) {
                bf16x8 sh = *(const bf16x8*)&shi_sh[cur][32 * kt + 8 * gi];
                bf16x8 sl = *(const bf16x8*)&slo_sh[cur][32 * kt + 8 * gi];
                gacc = __builtin_amdgcn_mfma_f32_16x16x32_bf16(ah, sh, gacc, 0, 0, 0);
                gacc = __builtin_amdgcn_mfma_f32_16x16x32_bf16(al, sh, gacc, 0, 0, 0);
                gacc = __builtin_amdgcn_mfma_f32_16x16x32_bf16(ah, sl, gacc, 0, 0, 0);
            }
        }
        if (w < 4 && li == 0) *(f32x4*)&gpart_sh[w][4 * gi] = gacc;
        __syncthreads();  // B2: gpart visible; all hA/s reads done

        // ---- gate (redundant per thread) ----
        f32x4 gp = *(const f32x4*)&gpart_sh[0][4 * gi];
        gp += *(const f32x4*)&gpart_sh[1][4 * gi];
        gp += *(const f32x4*)&gpart_sh[2][4 * gi];
        gp += *(const f32x4*)&gpart_sh[3][4 * gi];
        f32x4 sk4 = *(const f32x4*)&sk_sh[cur][4 * gi];
        float g4[4];
#pragma unroll
        for (int reg = 0; reg < 4; ++reg)
            g4[reg] = 1.f / (1.f + __expf(-(gp[reg] + sk4[reg])));

        // ---- epilogue: upd = h + g*relu(acc+kV+sW), row sumsq partial ----
        const float sw = sW_sh[cur][16 * w + li];
        f32x4 upd;
        float ss[4];
#pragma unroll
        for (int reg = 0; reg < 4; ++reg) {
            float v = fmaxf(accA[reg] + accB[reg] + accC[reg] + kvreg[reg] + sw, 0.f);
            float u = fmaf(g4[reg], v, hreg[reg]);
            upd[reg] = u;
            ss[reg] = u * u;
        }
#pragma unroll
        for (int m = 1; m < 16; m <<= 1)
#pragma unroll
            for (int reg = 0; reg < 4; ++reg) ss[reg] += __shfl_xor(ss[reg], m);
        if (li == 0) {
            f32x4 rr = {ss[0], ss[1], ss[2], ss[3]};
            *(f32x4*)&rowsq_sh[w][4 * gi] = rr;
        }
        __syncthreads();  // B3: all wave partials visible

        f32x4 rq = *(const f32x4*)&rowsq_sh[0][4 * gi];
#pragma unroll
        for (int ww = 1; ww < 8; ++ww) rq += *(const f32x4*)&rowsq_sh[ww][4 * gi];
        float rinv[4];
#pragma unroll
        for (int reg = 0; reg < 4; ++reg)
            rinv[reg] = rsqrtf(fmaxf(rq[reg], 1e-12f));

        // ---- normalize, split bf16, write hA ----
        {
            const int kt_w = w >> 1;
            const int b23 = (2 * w + (li >> 3)) & 3;
            const int j = li & 7;
#pragma unroll
            for (int reg = 0; reg < 4; ++reg) {
                float hn = upd[reg] * rinv[reg];
                hreg[reg] = hn;
                unsigned u = __float_as_uint(hn);
                unsigned short hi = (unsigned short)(u >> 16);
                float rem = hn - __uint_as_float(u & 0xffff0000u);
                unsigned short lo = (unsigned short)(__float_as_uint(rem) >> 16);
                int le = (4 * gi + reg) | (b23 << 4);
                int slot_w = le ^ ((le >> 2) & 3);
                hAhi[kt_w][slot_w][j] = hi;
                hAlo[kt_w][slot_w][j] = lo;
            }
        }
        // ---- stage next row into buffer nxt ----
        if (have) {
            if (t < 128) {
                unsigned u = __float_as_uint(pf);
                shi_sh[nxt][t] = (unsigned short)(u >> 16);
                float rem = pf - __uint_as_float(u & 0xffff0000u);
                slo_sh[nxt][t] = (unsigned short)(__float_as_uint(rem) >> 16);
            } else if (t < 256) {
                sW_sh[nxt][t - 128] = pf;
            } else if (t < 272) {
                sk_sh[nxt][t - 256] = pf;
            }
        }
        __syncthreads();  // B1: hA + staged rows visible
    }

    // ---- final h -> out ----
#pragma unroll
    for (int reg = 0; reg < 4; ++reg)
        out[((size_t)b * KK + 16 * rg + 4 * gi + reg) * DD + 16 * w + li] = hreg[reg];
}

// ---------------------------------------------------------------------------
extern "C" void kernel_launch(void* const* d_in, const int* in_sizes, int n_in,
                              void* d_out, int out_size, void* d_ws, size_t ws_size,
                              hipStream_t stream)
{
    const float* enc  = (const float*)d_in[0];  // [B,S,D]
    const int*   mask = (const int*)  d_in[1];  // [B,S]
    const float* keys = (const float*)d_in[2];  // [B,K,D]
    const float* U    = (const float*)d_in[3];  // [D,D]
    const float* V    = (const float*)d_in[4];  // [D,D]
    const float* W    = (const float*)d_in[5];  // [D,D]
    float* out = (float*)d_out;

    // ws layout: sW [B,S,D] | sk [B,S,K] | kV [B,K,D] | Ufh | Ufl
    float* sW = (float*)d_ws;
    float* sk = sW + (size_t)BB * SS * DD;
    float* kV = sk + (size_t)BB * SS * KK;
    unsigned short* Ufh = (unsigned short*)(kV + (size_t)BB * KK * DD);
    unsigned short* Ufl = Ufh + 8 * 4 * 64 * 8;

    kv_kernel<<<BB, 256, 0, stream>>>(keys, V, kV);
    swsk_kernel<<<BB * 4, 256, 0, stream>>>(enc, W, keys, sW, sk);
    ufrag_kernel<<<32, 64, 0, stream>>>(U, Ufh, Ufl);
    entnet_main<<<BB * 4, 512, 0, stream>>>(enc, mask, sW, sk, kV, Ufh, Ufl, out);
}

// Round 6
// 779.672 us; speedup vs baseline: 1.0093x; 1.0093x over previous
//
#include <hip/hip_runtime.h>
#include <math.h>

#define BB 256
#define SS 256
#define KK 64
#define DD 128

typedef short bf16x8 __attribute__((ext_vector_type(8)));
typedef float f32x4 __attribute__((ext_vector_type(4)));
typedef int   i32x4 __attribute__((ext_vector_type(4)));

__device__ __forceinline__ unsigned short bf16_rne(float x) {
  unsigned u = __float_as_uint(x);
  unsigned r = ((u >> 16) & 1u) + 0x7fffu;
  return (unsigned short)((u + r) >> 16);
}

// ---------------------------------------------------------------------------
// Precompute 1: kV[b,k,e] = sum_d keys[b,k,d] * V[d,e]   (fp32)
// ---------------------------------------------------------------------------
__global__ __launch_bounds__(256) void kv_kernel(const float* __restrict__ keys,
                                                 const float* __restrict__ V,
                                                 float* __restrict__ kV)
{
    __shared__ __align__(16) float Ks[KK][DD];
    __shared__ __align__(16) float Vs[DD][DD];
    const int b = blockIdx.x;
    const int t = threadIdx.x;
    const float* kb = keys + (size_t)b * KK * DD;
    for (int i = t; i < KK * DD / 4; i += 256) ((float4*)Ks)[i] = ((const float4*)kb)[i];
    for (int i = t; i < DD * DD / 4; i += 256) ((float4*)Vs)[i] = ((const float4*)V)[i];
    __syncthreads();

    const int e0 = (t & 15) * 8;
    const int k0 = (t >> 4) * 4;
    float acc[4][8];
#pragma unroll
    for (int i = 0; i < 4; ++i)
#pragma unroll
        for (int j = 0; j < 8; ++j) acc[i][j] = 0.f;

#pragma unroll 4
    for (int d = 0; d < DD; ++d) {
        float aa[4] = {Ks[k0 + 0][d], Ks[k0 + 1][d], Ks[k0 + 2][d], Ks[k0 + 3][d]};
        float4 v0 = *(const float4*)&Vs[d][e0];
        float4 v1 = *(const float4*)&Vs[d][e0 + 4];
        float vv[8] = {v0.x, v0.y, v0.z, v0.w, v1.x, v1.y, v1.z, v1.w};
#pragma unroll
        for (int i = 0; i < 4; ++i)
#pragma unroll
            for (int j = 0; j < 8; ++j) acc[i][j] = fmaf(aa[i], vv[j], acc[i][j]);
    }
    float* o = kV + (size_t)b * KK * DD;
#pragma unroll
    for (int i = 0; i < 4; ++i)
#pragma unroll
        for (int j = 0; j < 8; j += 4) {
            float4 w4 = {acc[i][j], acc[i][j + 1], acc[i][j + 2], acc[i][j + 3]};
            *(float4*)&o[(k0 + i) * DD + e0 + j] = w4;
        }
}

// ---------------------------------------------------------------------------
// Precompute 2 (fused): sW[b,t,e] = enc[b,t,:]@W ; sk[b,t,k] = enc[b,t,:].keys[b,k,:]
// ---------------------------------------------------------------------------
__global__ __launch_bounds__(256) void swsk_kernel(const float* __restrict__ enc,
                                                   const float* __restrict__ W,
                                                   const float* __restrict__ keys,
                                                   float* __restrict__ sW,
                                                   float* __restrict__ sk)
{
    __shared__ __align__(16) float Es[64][DD];   // 32 KB
    __shared__ __align__(16) float Ws[DD][DD];   // 64 KB (phase 2: reused for Ks)
    const int blk = blockIdx.x;
    const int b = blk >> 2;
    const int tt = blk & 3;
    const int t = threadIdx.x;
    const float* eb = enc + ((size_t)b * SS + tt * 64) * DD;
    for (int i = t; i < 64 * DD / 4; i += 256) ((float4*)Es)[i] = ((const float4*)eb)[i];
    for (int i = t; i < DD * DD / 4; i += 256) ((float4*)Ws)[i] = ((const float4*)W)[i];
    __syncthreads();

    // ---- phase 1: sW ----
    {
        const int e0 = (t & 15) * 8;
        const int r0 = (t >> 4) * 4;
        float acc[4][8];
#pragma unroll
        for (int i = 0; i < 4; ++i)
#pragma unroll
            for (int j = 0; j < 8; ++j) acc[i][j] = 0.f;
#pragma unroll 4
        for (int d = 0; d < DD; ++d) {
            float aa[4] = {Es[r0 + 0][d], Es[r0 + 1][d], Es[r0 + 2][d], Es[r0 + 3][d]};
            float4 v0 = *(const float4*)&Ws[d][e0];
            float4 v1 = *(const float4*)&Ws[d][e0 + 4];
            float vv[8] = {v0.x, v0.y, v0.z, v0.w, v1.x, v1.y, v1.z, v1.w};
#pragma unroll
            for (int i = 0; i < 4; ++i)
#pragma unroll
                for (int j = 0; j < 8; ++j) acc[i][j] = fmaf(aa[i], vv[j], acc[i][j]);
        }
        float* o = sW + ((size_t)b * SS + tt * 64) * DD;
#pragma unroll
        for (int i = 0; i < 4; ++i)
#pragma unroll
            for (int j = 0; j < 8; j += 4) {
                float4 w4 = {acc[i][j], acc[i][j + 1], acc[i][j + 2], acc[i][j + 3]};
                *(float4*)&o[(r0 + i) * DD + e0 + j] = w4;
            }
    }
    __syncthreads();
    // ---- phase 2: stage keys over Ws, compute sk ----
    {
        float (*Ks)[DD] = (float(*)[DD])Ws;
        const float* kb = keys + (size_t)b * KK * DD;
        for (int i = t; i < KK * DD / 4; i += 256) ((float4*)Ks)[i] = ((const float4*)kb)[i];
        __syncthreads();

        const int r0 = (t >> 4) * 4;
        const int k0 = (t & 15) * 4;
        float acc[4][4];
#pragma unroll
        for (int i = 0; i < 4; ++i)
#pragma unroll
            for (int j = 0; j < 4; ++j) acc[i][j] = 0.f;
#pragma unroll 4
        for (int d = 0; d < DD; ++d) {
            float er[4], kr[4];
#pragma unroll
            for (int i = 0; i < 4; ++i) er[i] = Es[r0 + i][d];
#pragma unroll
            for (int j = 0; j < 4; ++j) kr[j] = Ks[k0 + j][d];
#pragma unroll
            for (int i = 0; i < 4; ++i)
#pragma unroll
                for (int j = 0; j < 4; ++j) acc[i][j] = fmaf(er[i], kr[j], acc[i][j]);
        }
        float* o = sk + ((size_t)b * SS + tt * 64) * KK;
#pragma unroll
        for (int i = 0; i < 4; ++i) {
            float4 w4 = {acc[i][0], acc[i][1], acc[i][2], acc[i][3]};
            *(float4*)&o[(r0 + i) * KK + k0] = w4;
        }
    }
}

// ---------------------------------------------------------------------------
// Precompute 3: U in MFMA B-fragment order, split bf16 hi/lo.
// Ufh/Ufl layout: [ntg(8)][kt(4)][lane(64)][j(8)], value =
//   U[32*kt + 8*(lane>>4) + j][16*ntg + (lane&15)]
// ---------------------------------------------------------------------------
__global__ void ufrag_kernel(const float* __restrict__ U,
                             unsigned short* __restrict__ Ufh,
                             unsigned short* __restrict__ Ufl)
{
    const int blk = blockIdx.x;       // 32 = ntg*4 + kt
    const int l = threadIdx.x;        // 64
    const int ntg = blk >> 2, kt = blk & 3;
    const int e = ntg * 16 + (l & 15);
    const int d0 = kt * 32 + (l >> 4) * 8;
#pragma unroll
    for (int j = 0; j < 8; ++j) {
        float x = U[(d0 + j) * DD + e];
        unsigned short hi = bf16_rne(x);
        float rem = x - __uint_as_float(((unsigned)hi) << 16);
        unsigned short lo = bf16_rne(rem);
        int idx = (blk * 64 + l) * 8 + j;
        Ufh[idx] = hi;
        Ufl[idx] = lo;
    }
}

// ---------------------------------------------------------------------------
// Main kernel — R4 structure (post-timing-stable) + opaque asm register pins.
// Grid = 1024 (batch x 4 row-groups of 16 rows). 512 threads = 8 waves; wave
// w owns cols [16w,16w+16). U frags (32 VGPR) + kV are passed through an
// empty asm volatile with "+v" constraints after loading: they become opaque
// asm results, so the compiler can neither rematerialize the global loads
// inside the loop (R2/R4 failure: 25 GB FETCH) nor needs to spill (demand
// ~100 < 128 cap of launch_bounds(512,4)).
// Per step: MFMA (12 acc in 3 indep chains; wave w==kt adds 3 gate MFMA)
// -> B2 -> gate sigmoid (redundant), epilogue, sumsq partial -> B3 ->
// rsqrt, normalize, split-bf16 write to hA, stage next row -> B1.
// ---------------------------------------------------------------------------
__global__ __launch_bounds__(512, 4) void entnet_main(
    const float* __restrict__ enc,   // [B,S,D]
    const int*   __restrict__ mask,  // [B,S]
    const float* __restrict__ sWg,   // [B,S,D]
    const float* __restrict__ skg,   // [B,S,K]
    const float* __restrict__ kVg,   // [B,K,D]
    const unsigned short* __restrict__ Ufh,
    const unsigned short* __restrict__ Ufl,
    float*       __restrict__ out)   // [B,K,D]
{
    __shared__ __align__(16) unsigned short hAhi[4][64][8];   // 4 KB
    __shared__ __align__(16) unsigned short hAlo[4][64][8];   // 4 KB
    __shared__ __align__(16) unsigned short shi_sh[2][DD];
    __shared__ __align__(16) unsigned short slo_sh[2][DD];
    __shared__ __align__(16) float sW_sh[2][DD];
    __shared__ __align__(16) float sk_sh[2][16];
    __shared__ __align__(16) float gpart_sh[4][16];
    __shared__ __align__(16) float rowsq_sh[8][16];
    __shared__ int act_sh[SS];
    __shared__ int m_sh[SS];
    __shared__ int nact_sh;

    // XCD-grouped swizzle: 4 sibling blocks (same b) land on the same XCD.
    const int raw = blockIdx.x;
    const int xcd = raw & 7, slot = raw >> 3;
    const int b = xcd * 32 + (slot >> 2);
    const int rg = slot & 3;                 // rows k in [16rg, 16rg+16)

    const int t = threadIdx.x;
    const int w = t >> 6, l = t & 63;
    const int gi = l >> 4, li = l & 15;
    const int slot_r = l ^ ((l >> 2) & 3);

    // ---- stage mask, zero hA ----
    if (t < SS) m_sh[t] = mask[b * SS + t];
    {
        unsigned int* p = (unsigned int*)&hAhi[0][0][0];
        unsigned int* q = (unsigned int*)&hAlo[0][0][0];
        for (int i = t; i < 4 * 64 * 8 / 2; i += 512) { p[i] = 0u; q[i] = 0u; }
    }
    __syncthreads();
    if (t == 0) {
        int c = 0;
        for (int i = 0; i < SS; ++i) if (m_sh[i]) act_sh[c++] = i;
        nact_sh = c;
    }

    // ---- U fragments (regs): ntg = w, all kt -> 32 VGPR ----
    bf16x8 ufh[4], ufl[4];
#pragma unroll
    for (int kt = 0; kt < 4; ++kt) {
        int off = ((w * 4 + kt) * 64 + l) * 8;
        ufh[kt] = *(const bf16x8*)&Ufh[off];
        ufl[kt] = *(const bf16x8*)&Ufl[off];
    }
    // ---- kV (regs): k = 16rg+4gi+reg, e = 16w+li ----
    float kvreg[4];
#pragma unroll
    for (int reg = 0; reg < 4; ++reg)
        kvreg[reg] = kVg[((size_t)b * KK + 16 * rg + 4 * gi + reg) * DD + 16 * w + li];

    // Opaque pin: values become asm outputs -> not rematerializable, must
    // stay resident in VGPRs for the whole kernel.
#pragma unroll
    for (int kt = 0; kt < 4; ++kt) {
        asm volatile("" : "+v"(*(i32x4*)&ufh[kt]), "+v"(*(i32x4*)&ufl[kt]));
    }
    asm volatile("" : "+v"(kvreg[0]), "+v"(kvreg[1]), "+v"(kvreg[2]), "+v"(kvreg[3]));

    f32x4 hreg = (f32x4){0.f, 0.f, 0.f, 0.f};
    __syncthreads();

    const int nact = nact_sh;
    // ---- prologue: stage rows for act[0] into buffer 0 ----
    if (nact > 0) {
        int t0i = act_sh[0];
        if (t < 128) {
            float x = enc[((size_t)b * SS + t0i) * DD + t];
            unsigned u = __float_as_uint(x);
            shi_sh[0][t] = (unsigned short)(u >> 16);
            float rem = x - __uint_as_float(u & 0xffff0000u);
            slo_sh[0][t] = (unsigned short)(__float_as_uint(rem) >> 16);
        } else if (t < 256) {
            sW_sh[0][t - 128] = sWg[((size_t)b * SS + t0i) * DD + (t - 128)];
        } else if (t < 272) {
            sk_sh[0][t - 256] = skg[((size_t)b * SS + t0i) * KK + 16 * rg + (t - 256)];
        }
    }
    __syncthreads();

    for (int ai = 0; ai < nact; ++ai) {
        const int cur = ai & 1, nxt = cur ^ 1;
        // prefetch next active row (consumed after B3)
        float pf = 0.f;
        const bool have = (ai + 1 < nact);
        if (have) {
            int tn = act_sh[ai + 1];
            if (t < 128)      pf = enc[((size_t)b * SS + tn) * DD + t];
            else if (t < 256) pf = sWg[((size_t)b * SS + tn) * DD + (t - 128)];
            else if (t < 272) pf = skg[((size_t)b * SS + tn) * KK + 16 * rg + (t - 256)];
        }

        // ---- MFMA phase: 3 independent chains + gate partial (wave==kt) ----
        f32x4 accA = (f32x4){0.f, 0.f, 0.f, 0.f};
        f32x4 accB = (f32x4){0.f, 0.f, 0.f, 0.f};
        f32x4 accC = (f32x4){0.f, 0.f, 0.f, 0.f};
        f32x4 gacc = (f32x4){0.f, 0.f, 0.f, 0.f};
#pragma unroll
        for (int kt = 0; kt < 4; ++kt) {
            bf16x8 ah = *(const bf16x8*)&hAhi[kt][slot_r][0];
            bf16x8 al = *(const bf16x8*)&hAlo[kt][slot_r][0];
            accA = __builtin_amdgcn_mfma_f32_16x16x32_bf16(ah, ufh[kt], accA, 0, 0, 0);
            accB = __builtin_amdgcn_mfma_f32_16x16x32_bf16(al, ufh[kt], accB, 0, 0, 0);
            accC = __builtin_amdgcn_mfma_f32_16x16x32_bf16(ah, ufl[kt], accC, 0, 0, 0);
            if (w == kt) {
                bf16x8 sh = *(const bf16x8*)&shi_sh[cur][32 * kt + 8 * gi];
                bf16x8 sl = *(const bf16x8*)&slo_sh[cur][32 * kt + 8 * gi];
                gacc = __builtin_amdgcn_mfma_f32_16x16x32_bf16(ah, sh, gacc, 0, 0, 0);
                gacc = __builtin_amdgcn_mfma_f32_16x16x32_bf16(al, sh, gacc, 0, 0, 0);
                gacc = __builtin_amdgcn_mfma_f32_16x16x32_bf16(ah, sl, gacc, 0, 0, 0);
            }
        }
        if (w < 4 && li == 0) *(f32x4*)&gpart_sh[w][4 * gi] = gacc;
        __syncthreads();  // B2: gpart visible; all hA/s reads done

        // ---- gate (redundant per thread) ----
        f32x4 gp = *(const f32x4*)&gpart_sh[0][4 * gi];
        gp += *(const f32x4*)&gpart_sh[1][4 * gi];
        gp += *(const f32x4*)&gpart_sh[2][4 * gi];
        gp += *(const f32x4*)&gpart_sh[3][4 * gi];
        f32x4 sk4 = *(const f32x4*)&sk_sh[cur][4 * gi];
        float g4[4];
#pragma unroll
        for (int reg = 0; reg < 4; ++reg)
            g4[reg] = 1.f / (1.f + __expf(-(gp[reg] + sk4[reg])));

        // ---- epilogue: upd = h + g*relu(acc+kV+sW), row sumsq partial ----
        const float sw = sW_sh[cur][16 * w + li];
        f32x4 upd;
        float ss[4];
#pragma unroll
        for (int reg = 0; reg < 4; ++reg) {
            float v = fmaxf(accA[reg] + accB[reg] + accC[reg] + kvreg[reg] + sw, 0.f);
            float u = fmaf(g4[reg], v, hreg[reg]);
            upd[reg] = u;
            ss[reg] = u * u;
        }
#pragma unroll
        for (int m = 1; m < 16; m <<= 1)
#pragma unroll
            for (int reg = 0; reg < 4; ++reg) ss[reg] += __shfl_xor(ss[reg], m);
        if (li == 0) {
            f32x4 rr = {ss[0], ss[1], ss[2], ss[3]};
            *(f32x4*)&rowsq_sh[w][4 * gi] = rr;
        }
        __syncthreads();  // B3: all wave partials visible

        f32x4 rq = *(const f32x4*)&rowsq_sh[0][4 * gi];
#pragma unroll
        for (int ww = 1; ww < 8; ++ww) rq += *(const f32x4*)&rowsq_sh[ww][4 * gi];
        float rinv[4];
#pragma unroll
        for (int reg = 0; reg < 4; ++reg)
            rinv[reg] = rsqrtf(fmaxf(rq[reg], 1e-12f));

        // ---- normalize, split bf16, write hA ----
        {
            const int kt_w = w >> 1;
            const int b23 = (2 * w + (li >> 3)) & 3;
            const int j = li & 7;
#pragma unroll
            for (int reg = 0; reg < 4; ++reg) {
                float hn = upd[reg] * rinv[reg];
                hreg[reg] = hn;
                unsigned u = __float_as_uint(hn);
                unsigned short hi = (unsigned short)(u >> 16);
                float rem = hn - __uint_as_float(u & 0xffff0000u);
                unsigned short lo = (unsigned short)(__float_as_uint(rem) >> 16);
                int le = (4 * gi + reg) | (b23 << 4);
                int slot_w = le ^ ((le >> 2) & 3);
                hAhi[kt_w][slot_w][j] = hi;
                hAlo[kt_w][slot_w][j] = lo;
            }
        }
        // ---- stage next row into buffer nxt ----
        if (have) {
            if (t < 128) {
                unsigned u = __float_as_uint(pf);
                shi_sh[nxt][t] = (unsigned short)(u >> 16);
                float rem = pf - __uint_as_float(u & 0xffff0000u);
                slo_sh[nxt][t] = (unsigned short)(__float_as_uint(rem) >> 16);
            } else if (t < 256) {
                sW_sh[nxt][t - 128] = pf;
            } else if (t < 272) {
                sk_sh[nxt][t - 256] = pf;
            }
        }
        __syncthreads();  // B1: hA + staged rows visible
    }

    // ---- final h -> out ----
#pragma unroll
    for (int reg = 0; reg < 4; ++reg)
        out[((size_t)b * KK + 16 * rg + 4 * gi + reg) * DD + 16 * w + li] = hreg[reg];
}

// ---------------------------------------------------------------------------
extern "C" void kernel_launch(void* const* d_in, const int* in_sizes, int n_in,
                              void* d_out, int out_size, void* d_ws, size_t ws_size,
                              hipStream_t stream)
{
    const float* enc  = (const float*)d_in[0];  // [B,S,D]
    const int*   mask = (const int*)  d_in[1];  // [B,S]
    const float* keys = (const float*)d_in[2];  // [B,K,D]
    const float* U    = (const float*)d_in[3];  // [D,D]
    const float* V    = (const float*)d_in[4];  // [D,D]
    const float* W    = (const float*)d_in[5];  // [D,D]
    float* out = (float*)d_out;

    // ws layout: sW [B,S,D] | sk [B,S,K] | kV [B,K,D] | Ufh | Ufl
    float* sW = (float*)d_ws;
    float* sk = sW + (size_t)BB * SS * DD;
    float* kV = sk + (size_t)BB * SS * KK;
    unsigned short* Ufh = (unsigned short*)(kV + (size_t)BB * KK * DD);
    unsigned short* Ufl = Ufh + 8 * 4 * 64 * 8;

    kv_kernel<<<BB, 256, 0, stream>>>(keys, V, kV);
    swsk_kernel<<<BB * 4, 256, 0, stream>>>(enc, W, keys, sW, sk);
    ufrag_kernel<<<32, 64, 0, stream>>>(U, Ufh, Ufl);
    entnet_main<<<BB * 4, 512, 0, stream>>>(enc, mask, sW, sk, kV, Ufh, Ufl, out);
}

// Round 7
// 657.640 us; speedup vs baseline: 1.1966x; 1.1856x over previous
//
#include <hip/hip_runtime.h>
#include <math.h>

#define BB 256
#define SS 256
#define KK 64
#define DD 128

typedef short bf16x8 __attribute__((ext_vector_type(8)));
typedef float f32x4 __attribute__((ext_vector_type(4)));

__device__ __forceinline__ unsigned short bf16_rne(float x) {
  unsigned u = __float_as_uint(x);
  unsigned r = ((u >> 16) & 1u) + 0x7fffu;
  return (unsigned short)((u + r) >> 16);
}

// ---------------------------------------------------------------------------
// Precompute 1: kV[b,k,e] = sum_d keys[b,k,d] * V[d,e]   (fp32, proven)
// ---------------------------------------------------------------------------
__global__ __launch_bounds__(256) void kv_kernel(const float* __restrict__ keys,
                                                 const float* __restrict__ V,
                                                 float* __restrict__ kV)
{
    __shared__ __align__(16) float Ks[KK][DD];
    __shared__ __align__(16) float Vs[DD][DD];
    const int b = blockIdx.x;
    const int t = threadIdx.x;
    const float* kb = keys + (size_t)b * KK * DD;
    for (int i = t; i < KK * DD / 4; i += 256) ((float4*)Ks)[i] = ((const float4*)kb)[i];
    for (int i = t; i < DD * DD / 4; i += 256) ((float4*)Vs)[i] = ((const float4*)V)[i];
    __syncthreads();

    const int e0 = (t & 15) * 8;
    const int k0 = (t >> 4) * 4;
    float acc[4][8];
#pragma unroll
    for (int i = 0; i < 4; ++i)
#pragma unroll
        for (int j = 0; j < 8; ++j) acc[i][j] = 0.f;

#pragma unroll 4
    for (int d = 0; d < DD; ++d) {
        float aa[4] = {Ks[k0 + 0][d], Ks[k0 + 1][d], Ks[k0 + 2][d], Ks[k0 + 3][d]};
        float4 v0 = *(const float4*)&Vs[d][e0];
        float4 v1 = *(const float4*)&Vs[d][e0 + 4];
        float vv[8] = {v0.x, v0.y, v0.z, v0.w, v1.x, v1.y, v1.z, v1.w};
#pragma unroll
        for (int i = 0; i < 4; ++i)
#pragma unroll
            for (int j = 0; j < 8; ++j) acc[i][j] = fmaf(aa[i], vv[j], acc[i][j]);
    }
    float* o = kV + (size_t)b * KK * DD;
#pragma unroll
    for (int i = 0; i < 4; ++i)
#pragma unroll
        for (int j = 0; j < 8; j += 4) {
            float4 w4 = {acc[i][j], acc[i][j + 1], acc[i][j + 2], acc[i][j + 3]};
            *(float4*)&o[(k0 + i) * DD + e0 + j] = w4;
        }
}

// ---------------------------------------------------------------------------
// Precompute 2 (fused): sW[b,t,e] = enc[b,t,:]@W ; sk[b,t,k] = enc[b,t,:].keys[b,k,:]
// ---------------------------------------------------------------------------
__global__ __launch_bounds__(256) void swsk_kernel(const float* __restrict__ enc,
                                                   const float* __restrict__ W,
                                                   const float* __restrict__ keys,
                                                   float* __restrict__ sW,
                                                   float* __restrict__ sk)
{
    __shared__ __align__(16) float Es[64][DD];   // 32 KB
    __shared__ __align__(16) float Ws[DD][DD];   // 64 KB (phase 2: reused for Ks)
    const int blk = blockIdx.x;
    const int b = blk >> 2;
    const int tt = blk & 3;
    const int t = threadIdx.x;
    const float* eb = enc + ((size_t)b * SS + tt * 64) * DD;
    for (int i = t; i < 64 * DD / 4; i += 256) ((float4*)Es)[i] = ((const float4*)eb)[i];
    for (int i = t; i < DD * DD / 4; i += 256) ((float4*)Ws)[i] = ((const float4*)W)[i];
    __syncthreads();

    // ---- phase 1: sW ----
    {
        const int e0 = (t & 15) * 8;
        const int r0 = (t >> 4) * 4;
        float acc[4][8];
#pragma unroll
        for (int i = 0; i < 4; ++i)
#pragma unroll
            for (int j = 0; j < 8; ++j) acc[i][j] = 0.f;
#pragma unroll 4
        for (int d = 0; d < DD; ++d) {
            float aa[4] = {Es[r0 + 0][d], Es[r0 + 1][d], Es[r0 + 2][d], Es[r0 + 3][d]};
            float4 v0 = *(const float4*)&Ws[d][e0];
            float4 v1 = *(const float4*)&Ws[d][e0 + 4];
            float vv[8] = {v0.x, v0.y, v0.z, v0.w, v1.x, v1.y, v1.z, v1.w};
#pragma unroll
            for (int i = 0; i < 4; ++i)
#pragma unroll
                for (int j = 0; j < 8; ++j) acc[i][j] = fmaf(aa[i], vv[j], acc[i][j]);
        }
        float* o = sW + ((size_t)b * SS + tt * 64) * DD;
#pragma unroll
        for (int i = 0; i < 4; ++i)
#pragma unroll
            for (int j = 0; j < 8; j += 4) {
                float4 w4 = {acc[i][j], acc[i][j + 1], acc[i][j + 2], acc[i][j + 3]};
                *(float4*)&o[(r0 + i) * DD + e0 + j] = w4;
            }
    }
    __syncthreads();
    // ---- phase 2: stage keys over Ws, compute sk ----
    {
        float (*Ks)[DD] = (float(*)[DD])Ws;
        const float* kb = keys + (size_t)b * KK * DD;
        for (int i = t; i < KK * DD / 4; i += 256) ((float4*)Ks)[i] = ((const float4*)kb)[i];
        __syncthreads();

        const int r0 = (t >> 4) * 4;
        const int k0 = (t & 15) * 4;
        float acc[4][4];
#pragma unroll
        for (int i = 0; i < 4; ++i)
#pragma unroll
            for (int j = 0; j < 4; ++j) acc[i][j] = 0.f;
#pragma unroll 4
        for (int d = 0; d < DD; ++d) {
            float er[4], kr[4];
#pragma unroll
            for (int i = 0; i < 4; ++i) er[i] = Es[r0 + i][d];
#pragma unroll
            for (int j = 0; j < 4; ++j) kr[j] = Ks[k0 + j][d];
#pragma unroll
            for (int i = 0; i < 4; ++i)
#pragma unroll
                for (int j = 0; j < 4; ++j) acc[i][j] = fmaf(er[i], kr[j], acc[i][j]);
        }
        float* o = sk + ((size_t)b * SS + tt * 64) * KK;
#pragma unroll
        for (int i = 0; i < 4; ++i) {
            float4 w4 = {acc[i][0], acc[i][1], acc[i][2], acc[i][3]};
            *(float4*)&o[(r0 + i) * KK + k0] = w4;
        }
    }
}

// ---------------------------------------------------------------------------
// Precompute 3: U in MFMA B-fragment order, split bf16 hi/lo.
// Ufh/Ufl layout: [ntg(8)][kt(4)][lane(64)][j(8)], value =
//   U[32*kt + 8*(lane>>4) + j][16*ntg + (lane&15)]
// ---------------------------------------------------------------------------
__global__ void ufrag_kernel(const float* __restrict__ U,
                             unsigned short* __restrict__ Ufh,
                             unsigned short* __restrict__ Ufl)
{
    const int blk = blockIdx.x;       // 32 = ntg*4 + kt
    const int l = threadIdx.x;        // 64
    const int ntg = blk >> 2, kt = blk & 3;
    const int e = ntg * 16 + (l & 15);
    const int d0 = kt * 32 + (l >> 4) * 8;
#pragma unroll
    for (int j = 0; j < 8; ++j) {
        float x = U[(d0 + j) * DD + e];
        unsigned short hi = bf16_rne(x);
        float rem = x - __uint_as_float(((unsigned)hi) << 16);
        unsigned short lo = bf16_rne(rem);
        int idx = (blk * 64 + l) * 8 + j;
        Ufh[idx] = hi;
        Ufl[idx] = lo;
    }
}

// ---------------------------------------------------------------------------
// Main kernel. Grid = 256 (one batch per block, one block per CU).
// 1024 threads = 16 waves, 4 waves/SIMD (lockstep phases fill latency).
// Wave w: mt = w&3 (rows 16mt..+16), eq = w>>2 (cols 32eq..+32, nt 0..1).
// U fragments live in LDS (64 KB, staged once); h in fp32 regs + bf16 hi/lo
// LDS copy (A-frag layout, XOR slot swizzle). TWO barriers per step.
// Gate-carry: s.h_t = rinv*(s.upd) -> next step's gate dot is computed in
// the epilogue on unnormalized upd and carried in registers (no gate MFMA).
// s/sW/sk use a 3-slot rotation: step ai writes slot (ai+2)%3 (pre-B3),
// reads s from slot (ai+1)%3 and sW/sk from slot ai%3. Slot x is written at
// step x-2 and last read at step x; all write->read pairs cross >=2 barriers.
// ---------------------------------------------------------------------------
__global__ __launch_bounds__(1024) void entnet_main(
    const float* __restrict__ enc,   // [B,S,D]
    const int*   __restrict__ mask,  // [B,S]
    const float* __restrict__ sWg,   // [B,S,D]
    const float* __restrict__ skg,   // [B,S,K]
    const float* __restrict__ kVg,   // [B,K,D]
    const unsigned short* __restrict__ Ufh,
    const unsigned short* __restrict__ Ufl,
    float*       __restrict__ out)   // [B,K,D]
{
    __shared__ __align__(16) unsigned short hAhi[4][4][64][8];  // 16 KB [kt][mt]
    __shared__ __align__(16) unsigned short hAlo[4][4][64][8];  // 16 KB
    __shared__ __align__(16) unsigned short Uh_l[8][4][64][8];  // 32 KB [ntg][kt]
    __shared__ __align__(16) unsigned short Ul_l[8][4][64][8];  // 32 KB
    __shared__ __align__(16) float s3[3][DD];
    __shared__ __align__(16) float sW3[3][DD];
    __shared__ __align__(16) float sk3[3][KK];
    __shared__ __align__(16) float rowsq_sh[4][KK];
    __shared__ __align__(16) float gpsum_sh[4][KK];
    __shared__ int act_sh[SS];
    __shared__ int m_sh[SS];
    __shared__ int nact_sh;

    const int b = blockIdx.x;
    const int t = threadIdx.x;       // 0..1023
    const int l = t & 63;
    const int w = t >> 6;
    const int mt = w & 3, eq = w >> 2;
    const int gi = l >> 4, li = l & 15;
    const int slot_r = l ^ ((l >> 2) & 3);

    // ---- stage mask, U->LDS, zero hA ----
    if (t < SS) m_sh[t] = mask[b * SS + t];
    {
        const float4* gh = (const float4*)Ufh;     // 4096 float4 = 64 KB
        const float4* gl = (const float4*)Ufl;
        float4* lh = (float4*)&Uh_l[0][0][0][0];
        float4* ll = (float4*)&Ul_l[0][0][0][0];
        for (int i = t; i < 4096; i += 1024) { lh[i] = gh[i]; ll[i] = gl[i]; }
        unsigned int* ph = (unsigned int*)&hAhi[0][0][0][0];
        unsigned int* pl = (unsigned int*)&hAlo[0][0][0][0];
        for (int i = t; i < 4 * 4 * 64 * 8 / 2; i += 1024) { ph[i] = 0u; pl[i] = 0u; }
    }
    __syncthreads();
    if (t == 0) {
        int c = 0;
        for (int i = 0; i < SS; ++i) if (m_sh[i]) act_sh[c++] = i;
        nact_sh = c;
    }
    __syncthreads();
    const int nact = nact_sh;

    // ---- kV in regs: k = 16mt+4gi+reg, e = 32eq+16nt+li ----
    float kv[2][4];
#pragma unroll
    for (int nt = 0; nt < 2; ++nt)
#pragma unroll
        for (int reg = 0; reg < 4; ++reg)
            kv[nt][reg] = kVg[((size_t)b * KK + 16 * mt + 4 * gi + reg) * DD
                              + 32 * eq + 16 * nt + li];

    f32x4 hreg[2];
    hreg[0] = (f32x4){0.f, 0.f, 0.f, 0.f};
    hreg[1] = (f32x4){0.f, 0.f, 0.f, 0.f};
    float gpre[4] = {0.f, 0.f, 0.f, 0.f};   // s_act[ai] . h_prev for my 4 rows

    // ---- prologue: stage slots 0 (act0) and 1 (act1) ----
    if (nact > 0) {
        int a0 = act_sh[0];
        int a1 = (nact > 1) ? act_sh[1] : 0;
        if (t < 128) {
            s3[0][t] = enc[((size_t)b * SS + a0) * DD + t];
            if (nact > 1) s3[1][t] = enc[((size_t)b * SS + a1) * DD + t];
        } else if (t < 256) {
            sW3[0][t - 128] = sWg[((size_t)b * SS + a0) * DD + (t - 128)];
            if (nact > 1) sW3[1][t - 128] = sWg[((size_t)b * SS + a1) * DD + (t - 128)];
        } else if (t < 320) {
            sk3[0][t - 256] = skg[((size_t)b * SS + a0) * KK + (t - 256)];
            if (nact > 1) sk3[1][t - 256] = skg[((size_t)b * SS + a1) * KK + (t - 256)];
        }
    }
    __syncthreads();

    for (int ai = 0; ai < nact; ++ai) {
        const int sl0 = ai % 3, sl1 = (ai + 1) % 3, sl2 = (ai + 2) % 3;
        const bool have  = (ai + 1 < nact);
        const bool have2 = (ai + 2 < nact);

        // issue prefetch for act[ai+2] (LDS write happens just before B3)
        float pf = 0.f;
        if (have2) {
            int tn = act_sh[ai + 2];
            if (t < 128)      pf = enc[((size_t)b * SS + tn) * DD + t];
            else if (t < 256) pf = sWg[((size_t)b * SS + tn) * DD + (t - 128)];
            else if (t < 320) pf = skg[((size_t)b * SS + tn) * KK + (t - 256)];
        }

        // ---- gate: sigmoid(gpre + sk)  (register-carried dot product) ----
        f32x4 sk4 = *(const f32x4*)&sk3[sl0][16 * mt + 4 * gi];
        float g4[4];
#pragma unroll
        for (int reg = 0; reg < 4; ++reg)
            g4[reg] = 1.f / (1.f + __expf(-(gpre[reg] + sk4[reg])));

        // ---- MFMA: 3 chains x 2 nt, U frags from LDS ----
        f32x4 accA[2], accB[2], accC[2];
#pragma unroll
        for (int nt = 0; nt < 2; ++nt) {
            accA[nt] = (f32x4){0.f, 0.f, 0.f, 0.f};
            accB[nt] = (f32x4){0.f, 0.f, 0.f, 0.f};
            accC[nt] = (f32x4){0.f, 0.f, 0.f, 0.f};
        }
#pragma unroll
        for (int kt = 0; kt < 4; ++kt) {
            bf16x8 ah = *(const bf16x8*)&hAhi[kt][mt][slot_r][0];
            bf16x8 al = *(const bf16x8*)&hAlo[kt][mt][slot_r][0];
#pragma unroll
            for (int nt = 0; nt < 2; ++nt) {
                const int ntg = 2 * eq + nt;
                bf16x8 uh = *(const bf16x8*)&Uh_l[ntg][kt][l][0];
                bf16x8 ul = *(const bf16x8*)&Ul_l[ntg][kt][l][0];
                accA[nt] = __builtin_amdgcn_mfma_f32_16x16x32_bf16(ah, uh, accA[nt], 0, 0, 0);
                accB[nt] = __builtin_amdgcn_mfma_f32_16x16x32_bf16(al, uh, accB[nt], 0, 0, 0);
                accC[nt] = __builtin_amdgcn_mfma_f32_16x16x32_bf16(ah, ul, accC[nt], 0, 0, 0);
            }
        }

        // ---- epilogue: upd, sumsq + next-gate partials ----
        float sw2[2] = { sW3[sl0][32 * eq + li], sW3[sl0][32 * eq + 16 + li] };
        float sn2[2] = { have ? s3[sl1][32 * eq + li] : 0.f,
                         have ? s3[sl1][32 * eq + 16 + li] : 0.f };
        f32x4 upd[2];
        float ss[4] = {0.f, 0.f, 0.f, 0.f};
        float gp[4] = {0.f, 0.f, 0.f, 0.f};
#pragma unroll
        for (int nt = 0; nt < 2; ++nt)
#pragma unroll
            for (int reg = 0; reg < 4; ++reg) {
                float v = accA[nt][reg] + accB[nt][reg] + accC[nt][reg]
                          + kv[nt][reg] + sw2[nt];
                v = fmaxf(v, 0.f);
                float u = fmaf(g4[reg], v, hreg[nt][reg]);
                upd[nt][reg] = u;
                ss[reg] = fmaf(u, u, ss[reg]);
                gp[reg] = fmaf(sn2[nt], u, gp[reg]);
            }
#pragma unroll
        for (int m = 1; m < 16; m <<= 1)
#pragma unroll
            for (int reg = 0; reg < 4; ++reg) {
                ss[reg] += __shfl_xor(ss[reg], m);
                gp[reg] += __shfl_xor(gp[reg], m);
            }
        if (li == 0) {
            f32x4 rr = {ss[0], ss[1], ss[2], ss[3]};
            f32x4 gg = {gp[0], gp[1], gp[2], gp[3]};
            *(f32x4*)&rowsq_sh[eq][16 * mt + 4 * gi] = rr;
            *(f32x4*)&gpsum_sh[eq][16 * mt + 4 * gi] = gg;
        }
        // ---- stage slot sl2 (safe: slot free, see header proof) ----
        if (have2) {
            if (t < 128)      s3[sl2][t] = pf;
            else if (t < 256) sW3[sl2][t - 128] = pf;
            else if (t < 320) sk3[sl2][t - 256] = pf;
        }
        __syncthreads();   // B3: partials + staged slot visible

        f32x4 rq = *(const f32x4*)&rowsq_sh[0][16 * mt + 4 * gi];
        f32x4 gq = *(const f32x4*)&gpsum_sh[0][16 * mt + 4 * gi];
#pragma unroll
        for (int e2 = 1; e2 < 4; ++e2) {
            rq += *(const f32x4*)&rowsq_sh[e2][16 * mt + 4 * gi];
            gq += *(const f32x4*)&gpsum_sh[e2][16 * mt + 4 * gi];
        }
        float rinv[4];
#pragma unroll
        for (int reg = 0; reg < 4; ++reg) {
            rinv[reg] = rsqrtf(fmaxf(rq[reg], 1e-12f));
            gpre[reg] = gq[reg] * rinv[reg];
        }

        // ---- normalize, split bf16, write hA (stripe kt=eq, mt) ----
        {
            const int j = li & 7;
#pragma unroll
            for (int nt = 0; nt < 2; ++nt) {
                const int b23 = 2 * nt + (li >> 3);
#pragma unroll
                for (int reg = 0; reg < 4; ++reg) {
                    float hn = upd[nt][reg] * rinv[reg];
                    hreg[nt][reg] = hn;
                    unsigned u = __float_as_uint(hn);
                    unsigned short hi = (unsigned short)(u >> 16);
                    float rem = hn - __uint_as_float(u & 0xffff0000u);
                    unsigned short lo = (unsigned short)(__float_as_uint(rem) >> 16);
                    int le = (4 * gi + reg) | (b23 << 4);
                    int sw_ = le ^ ((le >> 2) & 3);
                    hAhi[eq][mt][sw_][j] = hi;
                    hAlo[eq][mt][sw_][j] = lo;
                }
            }
        }
        __syncthreads();   // B1: hA visible for next step's MFMA
    }

    // ---- final h -> out ----
#pragma unroll
    for (int nt = 0; nt < 2; ++nt)
#pragma unroll
        for (int reg = 0; reg < 4; ++reg)
            out[((size_t)b * KK + 16 * mt + 4 * gi + reg) * DD
                + 32 * eq + 16 * nt + li] = hreg[nt][reg];
}

// ---------------------------------------------------------------------------
extern "C" void kernel_launch(void* const* d_in, const int* in_sizes, int n_in,
                              void* d_out, int out_size, void* d_ws, size_t ws_size,
                              hipStream_t stream)
{
    const float* enc  = (const float*)d_in[0];  // [B,S,D]
    const int*   mask = (const int*)  d_in[1];  // [B,S]
    const float* keys = (const float*)d_in[2];  // [B,K,D]
    const float* U    = (const float*)d_in[3];  // [D,D]
    const float* V    = (const float*)d_in[4];  // [D,D]
    const float* W    = (const float*)d_in[5];  // [D,D]
    float* out = (float*)d_out;

    // ws layout: sW [B,S,D] | sk [B,S,K] | kV [B,K,D] | Ufh | Ufl
    float* sW = (float*)d_ws;
    float* sk = sW + (size_t)BB * SS * DD;
    float* kV = sk + (size_t)BB * SS * KK;
    unsigned short* Ufh = (unsigned short*)(kV + (size_t)BB * KK * DD);
    unsigned short* Ufl = Ufh + 8 * 4 * 64 * 8;

    kv_kernel<<<BB, 256, 0, stream>>>(keys, V, kV);
    swsk_kernel<<<BB * 4, 256, 0, stream>>>(enc, W, keys, sW, sk);
    ufrag_kernel<<<32, 64, 0, stream>>>(U, Ufh, Ufl);
    entnet_main<<<BB, 1024, 0, stream>>>(enc, mask, sW, sk, kV, Ufh, Ufl, out);
}